// Round 18
// baseline (214.173 us; speedup 1.0000x reference)
//
#include <hip/hip_runtime.h>
#include <hip/hip_bf16.h>
#include <math.h>

#define S_LEN 2048
#define HIDW 2048
#define NHEAD 16
#define NKVH 4
#define HD 128
#define NB 2
#define MROWS (NB * S_LEN)                 // 4096
#define QKVN (NHEAD * HD + 2 * NKVH * HD)  // 3072
#define KOFF (NHEAD * HD)                  // 2048
#define VOFF (NHEAD * HD + NKVH * HD)      // 2560

typedef __bf16 bf16_t;
typedef __bf16 bf16x8_t __attribute__((ext_vector_type(8)));
typedef float f32x4_t __attribute__((ext_vector_type(4)));

__device__ __forceinline__ void gload_lds16(const bf16_t* g, bf16_t* l) {
  __builtin_amdgcn_global_load_lds(
      (const __attribute__((address_space(1))) void*)g,
      (__attribute__((address_space(3))) void*)l, 16, 0, 0);
}

__device__ __forceinline__ f32x4_t zero4() {
  f32x4_t z = {0.f, 0.f, 0.f, 0.f};
  return z;
}

__device__ __forceinline__ float fexp2(float x) {
#if __has_builtin(__builtin_amdgcn_exp2f)
  return __builtin_amdgcn_exp2f(x);
#else
  return exp2f(x);
#endif
}

// ---------------- convert x (f32 -> bf16), 8 elems/thread ----------------
__global__ __launch_bounds__(256) void k_cvt8(const float* __restrict__ in,
                                              bf16_t* __restrict__ out, int n8) {
  int i = blockIdx.x * 256 + threadIdx.x;
  if (i >= n8) return;
  const float4* p = (const float4*)(in + (size_t)i * 8);
  float4 a = p[0], b = p[1];
  bf16x8_t r;
  r[0] = (bf16_t)a.x; r[1] = (bf16_t)a.y; r[2] = (bf16_t)a.z; r[3] = (bf16_t)a.w;
  r[4] = (bf16_t)b.x; r[5] = (bf16_t)b.y; r[6] = (bf16_t)b.z; r[7] = (bf16_t)b.w;
  *(bf16x8_t*)(out + (size_t)i * 8) = r;
}

// ---------------- transpose + convert: in f32 [R][C] -> out bf16 [C][R] ----
__global__ __launch_bounds__(256) void k_tr_cvt(const float* __restrict__ in,
                                                bf16_t* __restrict__ out, int R, int C) {
  __shared__ float t[32][33];
  int c0 = blockIdx.x * 32, r0 = blockIdx.y * 32;
  int tx = threadIdx.x & 31, ty = threadIdx.x >> 5;
#pragma unroll
  for (int rr = ty; rr < 32; rr += 8) t[rr][tx] = in[(size_t)(r0 + rr) * C + c0 + tx];
  __syncthreads();
#pragma unroll
  for (int rr = ty; rr < 32; rr += 8)
    out[(size_t)(c0 + rr) * R + r0 + tx] = (bf16_t)t[tx][rr];
}

// ---------------- GEMM BMx256 tile (BM = BMH*128), BK=64, 8 waves ----------
// R13 counted-vmcnt 4-phase schedule (best measured of 6 variants: 94 us).
// EPI=0: f32 out. EPI=2: fused rope epilogue (cos/sin staged in dead LDS).
template <int EPI, int BMH>
__global__ __launch_bounds__(512, 2) void k_gemm256(const bf16_t* __restrict__ A,
                                                    const bf16_t* __restrict__ Bt,
                                                    void* __restrict__ Cout,
                                                    int M, int N, int K, int nby,
                                                    const float* __restrict__ cosT,
                                                    const float* __restrict__ sinT) {
  __shared__ bf16_t As[2][BMH * 128 * 64];
  __shared__ bf16_t Bs[2][256 * 64];

  int tid = threadIdx.x;
  int lane = tid & 63, wid = tid >> 6;
  int l15 = lane & 15, lg = lane >> 4;
  int wrb = (wid >> 2) * (BMH * 64);
  int wcb = (wid & 3) * 64;

  int nwg = gridDim.x;
  int qx = nwg >> 3;
  int lin = blockIdx.x;
  int wg = (lin & 7) * qx + (lin >> 3);
  int row0 = (wg / nby) * (BMH * 128), col0 = (wg % nby) * 256;

  int srow = tid >> 3;
  int scol = ((tid & 7) ^ (srow & 7)) * 8;
  const bf16_t* Ag = A + (size_t)(row0 + srow) * K + scol;
  const bf16_t* Bg = Bt + (size_t)(col0 + srow) * K + scol;

  f32x4_t acc[BMH * 4][4];
#pragma unroll
  for (int i = 0; i < BMH * 4; i++)
#pragma unroll
    for (int j = 0; j < 4; j++) acc[i][j] = zero4();

  int xr = (l15 & 7) << 4;
  int nk = K >> 6;

  auto stA = [&](int tt, int u) {
    gload_lds16(Ag + (size_t)u * 64 * K + (size_t)tt * 64,
                As[tt & 1] + u * 4096 + tid * 8);
  };
  auto stB = [&](int tt, int u) {
    gload_lds16(Bg + (size_t)u * 64 * K + (size_t)tt * 64,
                Bs[tt & 1] + u * 4096 + tid * 8);
  };

  // prologue: stage tiles 0 and 1 fully; wait tile 0 (tile 1 stays in flight)
  for (int tt = 0; tt < 2 && tt < nk; tt++) {
    for (int u = 0; u < BMH * 2; u++) stA(tt, u);
    for (int u = 0; u < 4; u++) stB(tt, u);
  }
  if (nk > 1) {
    if constexpr (BMH == 2) asm volatile("s_waitcnt vmcnt(8)" ::: "memory");
    else asm volatile("s_waitcnt vmcnt(6)" ::: "memory");
  } else {
    asm volatile("s_waitcnt vmcnt(0)" ::: "memory");
  }
  __builtin_amdgcn_s_barrier();
  __builtin_amdgcn_sched_barrier(0);

  for (int t = 0; t < nk; t++) {
    const char* Ac = (const char*)As[t & 1];
    const char* Bc = (const char*)Bs[t & 1];
    bool pf = (t + 2 < nk);

    // P1: ds_read af0 + ALL B-frags; MFMA (mh0, nh0)
    bf16x8_t af0[4][2], bfr[4][2];
#pragma unroll
    for (int i = 0; i < 4; i++) {
      int row = wrb + i * 16 + l15;
#pragma unroll
      for (int kk = 0; kk < 2; kk++)
        af0[i][kk] = *(const bf16x8_t*)(Ac + ((row * 128 + kk * 64 + lg * 16) ^ xr));
    }
#pragma unroll
    for (int jn = 0; jn < 4; jn++) {
      int rowb = wcb + jn * 16 + l15;
#pragma unroll
      for (int kk = 0; kk < 2; kk++)
        bfr[jn][kk] = *(const bf16x8_t*)(Bc + ((rowb * 128 + kk * 64 + lg * 16) ^ xr));
    }
    __builtin_amdgcn_s_barrier();
    __builtin_amdgcn_s_setprio(1);
    if constexpr (BMH == 2) {
#pragma unroll
      for (int i = 0; i < 4; i++)
#pragma unroll
        for (int j = 0; j < 2; j++)
#pragma unroll
          for (int kk = 0; kk < 2; kk++)
            acc[i][j] = __builtin_amdgcn_mfma_f32_16x16x32_bf16(af0[i][kk], bfr[j][kk],
                                                                acc[i][j], 0, 0, 0);
    } else {
#pragma unroll
      for (int i = 0; i < 4; i++)
#pragma unroll
        for (int kk = 0; kk < 2; kk++)
          acc[i][0] = __builtin_amdgcn_mfma_f32_16x16x32_bf16(af0[i][kk], bfr[0][kk],
                                                              acc[i][0], 0, 0, 0);
    }
    __builtin_amdgcn_s_setprio(0);

    // P2: issue A granules freed at P1; MFMA (mh0, nh1)
    if (pf) {
      stA(t + 2, 0);
      if constexpr (BMH == 2) stA(t + 2, 2);
      else stA(t + 2, 1);
    }
    __builtin_amdgcn_s_barrier();
    __builtin_amdgcn_s_setprio(1);
    if constexpr (BMH == 2) {
#pragma unroll
      for (int i = 0; i < 4; i++)
#pragma unroll
        for (int j = 0; j < 2; j++)
#pragma unroll
          for (int kk = 0; kk < 2; kk++)
            acc[i][2 + j] = __builtin_amdgcn_mfma_f32_16x16x32_bf16(
                af0[i][kk], bfr[2 + j][kk], acc[i][2 + j], 0, 0, 0);
    } else {
#pragma unroll
      for (int i = 0; i < 4; i++)
#pragma unroll
        for (int kk = 0; kk < 2; kk++)
          acc[i][1] = __builtin_amdgcn_mfma_f32_16x16x32_bf16(af0[i][kk], bfr[1][kk],
                                                              acc[i][1], 0, 0, 0);
    }
    __builtin_amdgcn_s_setprio(0);

    // P3: (BMH=2) ds_read af1; issue B0,B1; MFMA
    bf16x8_t af1[4][2];
    if constexpr (BMH == 2) {
#pragma unroll
      for (int i = 0; i < 4; i++) {
        int row = wrb + 64 + i * 16 + l15;
#pragma unroll
        for (int kk = 0; kk < 2; kk++)
          af1[i][kk] = *(const bf16x8_t*)(Ac + ((row * 128 + kk * 64 + lg * 16) ^ xr));
      }
    }
    if (pf) { stB(t + 2, 0); stB(t + 2, 1); }
    __builtin_amdgcn_s_barrier();
    __builtin_amdgcn_s_setprio(1);
    if constexpr (BMH == 2) {
#pragma unroll
      for (int i = 0; i < 4; i++)
#pragma unroll
        for (int j = 0; j < 2; j++)
#pragma unroll
          for (int kk = 0; kk < 2; kk++)
            acc[4 + i][j] = __builtin_amdgcn_mfma_f32_16x16x32_bf16(
                af1[i][kk], bfr[j][kk], acc[4 + i][j], 0, 0, 0);
    } else {
#pragma unroll
      for (int i = 0; i < 4; i++)
#pragma unroll
        for (int kk = 0; kk < 2; kk++)
          acc[i][2] = __builtin_amdgcn_mfma_f32_16x16x32_bf16(af0[i][kk], bfr[2][kk],
                                                              acc[i][2], 0, 0, 0);
    }
    __builtin_amdgcn_s_setprio(0);

    // P4: issue B2,B3 (+A1,A3 for BMH=2); MFMA
    if (pf) {
      stB(t + 2, 2); stB(t + 2, 3);
      if constexpr (BMH == 2) { stA(t + 2, 1); stA(t + 2, 3); }
    }
    __builtin_amdgcn_s_barrier();
    __builtin_amdgcn_s_setprio(1);
    if constexpr (BMH == 2) {
#pragma unroll
      for (int i = 0; i < 4; i++)
#pragma unroll
        for (int j = 0; j < 2; j++)
#pragma unroll
          for (int kk = 0; kk < 2; kk++)
            acc[4 + i][2 + j] = __builtin_amdgcn_mfma_f32_16x16x32_bf16(
                af1[i][kk], bfr[2 + j][kk], acc[4 + i][2 + j], 0, 0, 0);
    } else {
#pragma unroll
      for (int i = 0; i < 4; i++)
#pragma unroll
        for (int kk = 0; kk < 2; kk++)
          acc[i][3] = __builtin_amdgcn_mfma_f32_16x16x32_bf16(af0[i][kk], bfr[3][kk],
                                                              acc[i][3], 0, 0, 0);
    }
    __builtin_amdgcn_s_setprio(0);

    // boundary: counted wait (t+2's loads stay in flight)
    if (t + 1 < nk) {
      if (pf) {
        if constexpr (BMH == 2) asm volatile("s_waitcnt vmcnt(8)" ::: "memory");
        else asm volatile("s_waitcnt vmcnt(6)" ::: "memory");
      } else {
        asm volatile("s_waitcnt vmcnt(0)" ::: "memory");
      }
    }
    __builtin_amdgcn_s_barrier();
    __builtin_amdgcn_sched_barrier(0);
  }

  if (EPI == 2) {
    if (col0 < VOFF) {
      // stage cos/sin rows [sbase, sbase+256) x 64 f32 into dead As/Bs LDS
      int sbase = row0 & (S_LEN - 1);
      bf16_t* cosL = &As[0][0];
      bf16_t* sinL = &Bs[0][0];
#pragma unroll
      for (int k = 0; k < 8; k++) {
        gload_lds16((const bf16_t*)(cosT + (size_t)sbase * 64 + k * 2048 + tid * 4),
                    cosL + k * 4096 + tid * 8);
        gload_lds16((const bf16_t*)(sinT + (size_t)sbase * 64 + k * 2048 + tid * 4),
                    sinL + k * 4096 + tid * 8);
      }
      asm volatile("s_waitcnt vmcnt(0)" ::: "memory");
      __builtin_amdgcn_s_barrier();
      const float* cosF = (const float*)cosL;
      const float* sinF = (const float*)sinL;
      const float QS = 0.08838834764831845f * 1.4426950408889634f;
#pragma unroll
      for (int i = 0; i < BMH * 4; i++) {
#pragma unroll
        for (int j = 0; j < 4; j++) {
          int c = col0 + wcb + j * 16 + l15;
          int rlb = wrb + i * 16 + lg * 4;
          float scale = (c < KOFF) ? QS : 1.0f;
          int p0 = (c & 127) >> 1;
          int codd = c & 1;
#pragma unroll
          for (int qd = 0; qd < 4; qd++) {
            int rl = rlb + qd;
            float self = acc[i][j][qd];
            float other = __shfl_xor(self, 1);
            float cv = cosF[rl * 64 + p0], sv = sinF[rl * 64 + p0];
            float outv = codd ? (self * cv + other * sv) : (self * cv - other * sv);
            ((bf16_t*)Cout)[(size_t)(row0 + rl) * N + c] = (bf16_t)(outv * scale);
          }
        }
      }
    } else {
      // pure-V block: plain bf16 store (transpose done by k_vt)
#pragma unroll
      for (int i = 0; i < BMH * 4; i++) {
#pragma unroll
        for (int j = 0; j < 4; j++) {
          int r = row0 + wrb + i * 16 + lg * 4;
          int c = col0 + wcb + j * 16 + l15;
#pragma unroll
          for (int qd = 0; qd < 4; qd++)
            ((bf16_t*)Cout)[(size_t)(r + qd) * N + c] = (bf16_t)acc[i][j][qd];
        }
      }
    }
  } else {
#pragma unroll
    for (int i = 0; i < BMH * 4; i++) {
#pragma unroll
      for (int j = 0; j < 4; j++) {
        int r = row0 + wrb + i * 16 + lg * 4;
        int c = col0 + wcb + j * 16 + l15;
#pragma unroll
        for (int qd = 0; qd < 4; qd++)
          ((float*)Cout)[(size_t)(r + qd) * N + c] = acc[i][j][qd];
      }
    }
  }
}

// ---------------- V -> Vt relayout: vt[b][kvh][d][s] -----------------------
__global__ __launch_bounds__(256) void k_vt(const bf16_t* __restrict__ qkv,
                                            bf16_t* __restrict__ vt) {
  __shared__ bf16_t t[32][33];
  int s0 = blockIdx.x * 32;
  int dt = (blockIdx.y & 3) * 32;
  int h = blockIdx.y >> 2;
  int b = blockIdx.z;
  int tx = threadIdx.x & 31, ty = threadIdx.x >> 5;
#pragma unroll
  for (int rr = ty; rr < 32; rr += 8)
    t[rr][tx] = qkv[(size_t)(b * S_LEN + s0 + rr) * QKVN + VOFF + h * HD + dt + tx];
  __syncthreads();
#pragma unroll
  for (int rr = ty; rr < 32; rr += 8)
    vt[((size_t)((b * NKVH + h) * HD + dt + rr)) * S_LEN + s0 + tx] = t[tx][rr];
}

// ------- flash attention: 4 waves, 2 q-subtiles/wave, QBLK=128 -------------
// Amortization WITHOUT occupancy loss (R17 lesson): keep 256-thr 4-wave
// blocks (73 KB -> 2 blocks/CU) but each wave owns TWO 16-row q-subtiles
// (rows qg*128+wid*16 and +64). Stage-iterations per (b,h): 528 -> 272; each
// staged K/V tile feeds 2x the compute. Sub0 skips its fully-masked tail
// tile (wave-uniform guard). Complementary pairing: all 512 blocks resident
// (2/CU); qg = (idx<256)? 15-p : p makes pair {c,c+256} work sum == 36.
// Swapped QK^T softmax (R12, verified).
__global__ __launch_bounds__(256, 2) void k_attn(const bf16_t* __restrict__ qkv,
                                                 const bf16_t* __restrict__ vt,
                                                 bf16_t* __restrict__ ctx) {
  __shared__ bf16_t Ks[2 * 64 * 128];   // 2 x 16 KB, swizzled [kv][d]
  __shared__ bf16_t Vs[2 * 128 * 64];   // 2 x 16 KB, swizzled [d][kv]
  __shared__ bf16_t plds[4][16 * 72];

  int tid = threadIdx.x;
  int lane = tid & 63, wid = tid >> 6;
  int idx = blockIdx.x;
  int bh = idx & 31;
  int p = (idx >> 5) & 7;
  int qg = (idx < 256) ? (15 - p) : p;
  int b = bh >> 4, h = bh & 15;
  int kvh = h >> 2;
  int l15 = lane & 15, lg = lane >> 4;
  int q0s[2] = {qg * 128 + wid * 16, qg * 128 + 64 + wid * 16};

  const bf16_t* Kbase = qkv + (size_t)(b * S_LEN) * QKVN + KOFF + kvh * HD;
  const bf16_t* Vbase = vt + (size_t)(b * NKVH + kvh) * HD * S_LEN;

  bf16x8_t aq[2][4];
#pragma unroll
  for (int s = 0; s < 2; s++) {
    const bf16_t* Qp = qkv + (size_t)(b * S_LEN + q0s[s] + l15) * QKVN + h * HD + lg * 8;
#pragma unroll
    for (int kk = 0; kk < 4; kk++) aq[s][kk] = *(const bf16x8_t*)(Qp + kk * 32);
  }

  int Ls[4], Lk[4], Lv[4];
#pragma unroll
  for (int u = 0; u < 4; u++) {
    int L = u * 4096 + tid * 16;
    Ls[u] = L >> 1;
    Lk[u] = L ^ (((L >> 8) & 7) << 4);
    Lv[u] = L ^ (((L >> 7) & 7) << 4);
  }

  f32x4_t o[2][8];
#pragma unroll
  for (int s = 0; s < 2; s++)
#pragma unroll
    for (int j = 0; j < 8; j++) o[s][j] = zero4();
  float ms[2] = {-INFINITY, -INFINITY}, lsum[2] = {0.f, 0.f};

  bf16_t* pbuf = &plds[wid][0];
  int xr = (l15 & 7) << 4;
  int ntiles = 2 * qg + 2;

#pragma unroll
  for (int u = 0; u < 4; u++) {
    gload_lds16(Kbase + (size_t)(Lk[u] >> 8) * QKVN + ((Lk[u] & 255) >> 1), Ks + Ls[u]);
    gload_lds16(Vbase + (size_t)(Lv[u] >> 7) * S_LEN + ((Lv[u] & 127) >> 1), Vs + Ls[u]);
  }
  __syncthreads();

  for (int t = 0; t < ntiles; t++) {
    int kv0 = t * 64;
    if (t + 1 < ntiles) {
      const bf16_t* Kn = Kbase + (size_t)(kv0 + 64) * QKVN;
      const bf16_t* Vn = Vbase + kv0 + 64;
      int bo = ((t + 1) & 1) * 8192;
#pragma unroll
      for (int u = 0; u < 4; u++) {
        gload_lds16(Kn + (size_t)(Lk[u] >> 8) * QKVN + ((Lk[u] & 255) >> 1), Ks + bo + Ls[u]);
        gload_lds16(Vn + (size_t)(Lv[u] >> 7) * S_LEN + ((Lv[u] & 127) >> 1), Vs + bo + Ls[u]);
      }
    }
    const char* Kb = (const char*)Ks + (t & 1) * 16384;
    const char* Vb = (const char*)Vs + (t & 1) * 16384;

#pragma unroll
    for (int s = 0; s < 2; s++) {
      int q0 = q0s[s];
      if (kv0 > q0 + 15) continue;  // wave-uniform skip (sub0's tail tile)
      int qcol = q0 + l15;

      // ---- QK^T swapped: sacc[cg][i] = S[kv=kv0+cg*16+lg*4+i][q=qcol] ----
      f32x4_t sacc[4];
#pragma unroll
      for (int cg = 0; cg < 4; cg++) sacc[cg] = zero4();
#pragma unroll
      for (int cg = 0; cg < 4; cg++) {
#pragma unroll
        for (int kk = 0; kk < 4; kk++) {
          int boff = ((cg * 16 + l15) * 256 + kk * 64 + lg * 16) ^ xr;
          bf16x8_t bk = *(const bf16x8_t*)(Kb + boff);
          sacc[cg] = __builtin_amdgcn_mfma_f32_16x16x32_bf16(bk, aq[s][kk], sacc[cg], 0, 0, 0);
        }
      }
      if (kv0 + 63 > q0) {
#pragma unroll
        for (int cg = 0; cg < 4; cg++) {
#pragma unroll
          for (int i = 0; i < 4; i++) {
            int kvg = kv0 + cg * 16 + lg * 4 + i;
            if (kvg > qcol) sacc[cg][i] = -1e30f;
          }
        }
      }
      // ---- online softmax: in-lane reduce + 2 shuffles ----
      float pmax = sacc[0][0];
#pragma unroll
      for (int cg = 0; cg < 4; cg++)
#pragma unroll
        for (int i = 0; i < 4; i++) pmax = fmaxf(pmax, sacc[cg][i]);
      pmax = fmaxf(pmax, __shfl_xor(pmax, 16));
      pmax = fmaxf(pmax, __shfl_xor(pmax, 32));
      if (__any(pmax - ms[s] > 8.0f)) {
        float nm = fmaxf(ms[s], pmax);
        float sc = fexp2(ms[s] - nm);
        ms[s] = nm;
        lsum[s] *= sc;
        float sci[4];
#pragma unroll
        for (int i = 0; i < 4; i++) sci[i] = __shfl(sc, lg * 4 + i);
#pragma unroll
        for (int j = 0; j < 8; j++)
#pragma unroll
          for (int i = 0; i < 4; i++) o[s][j][i] *= sci[i];
      }
      float ls = 0.f;
#pragma unroll
      for (int cg = 0; cg < 4; cg++)
#pragma unroll
        for (int i = 0; i < 4; i++) {
          sacc[cg][i] = fexp2(sacc[cg][i] - ms[s]);
          ls += sacc[cg][i];
        }
      ls += __shfl_xor(ls, 16);
      ls += __shfl_xor(ls, 32);
      lsum[s] += ls;
      // ---- P -> per-wave LDS (row = q = l15) ----
#pragma unroll
      for (int cg = 0; cg < 4; cg++)
#pragma unroll
        for (int i = 0; i < 4; i++)
          pbuf[l15 * 72 + cg * 16 + lg * 4 + i] = (bf16_t)sacc[cg][i];
      __builtin_amdgcn_wave_barrier();
      bf16x8_t pa0 = *(const bf16x8_t*)(pbuf + l15 * 72 + lg * 8);
      bf16x8_t pa1 = *(const bf16x8_t*)(pbuf + l15 * 72 + 32 + lg * 8);
      __builtin_amdgcn_wave_barrier();
#pragma unroll
      for (int j = 0; j < 8; j++) {
        int d = j * 16 + l15;
        int bo0 = (d * 128 + lg * 16) ^ xr;
        int bo1 = (d * 128 + 64 + lg * 16) ^ xr;
        o[s][j] = __builtin_amdgcn_mfma_f32_16x16x32_bf16(
            pa0, *(const bf16x8_t*)(Vb + bo0), o[s][j], 0, 0, 0);
        o[s][j] = __builtin_amdgcn_mfma_f32_16x16x32_bf16(
            pa1, *(const bf16x8_t*)(Vb + bo1), o[s][j], 0, 0, 0);
      }
    }
    __syncthreads();
  }

#pragma unroll
  for (int s = 0; s < 2; s++) {
    bf16_t* Cp = ctx + (size_t)(b * S_LEN + q0s[s]) * KOFF + h * HD;
#pragma unroll
    for (int i = 0; i < 4; i++) {
      float inv = 1.f / __shfl(lsum[s], lg * 4 + i);
      int row = lg * 4 + i;
#pragma unroll
      for (int j = 0; j < 8; j++)
        Cp[(size_t)row * KOFF + j * 16 + l15] = (bf16_t)(o[s][j][i] * inv);
    }
  }
}

extern "C" void kernel_launch(void* const* d_in, const int* in_sizes, int n_in,
                              void* d_out, int out_size, void* d_ws, size_t ws_size,
                              hipStream_t stream) {
  const float* x = (const float*)d_in[0];
  const float* wq = (const float*)d_in[1];
  const float* wk = (const float*)d_in[2];
  const float* wv = (const float*)d_in[3];
  const float* wo = (const float*)d_in[4];
  const float* cosT = (const float*)d_in[5];
  const float* sinT = (const float*)d_in[6];

  bf16_t* xb = (bf16_t*)d_ws;                          // 4096x2048 (later reused as ctx)
  bf16_t* wqkvT = xb + (size_t)MROWS * HIDW;           // 3072x2048
  bf16_t* woT = wqkvT + (size_t)QKVN * HIDW;           // 2048x2048
  bf16_t* qkv = woT + (size_t)HIDW * HIDW;             // 4096x3072
  bf16_t* vtb = qkv + (size_t)MROWS * QKVN;            // 2*4*128*2048

  // 1) convert x
  k_cvt8<<<MROWS * HIDW / 8 / 256, 256, 0, stream>>>(x, xb, MROWS * HIDW / 8);
  // 2) weight transposes (f32 -> bf16, [K][N] -> [N][K])
  k_tr_cvt<<<dim3(KOFF / 32, HIDW / 32), 256, 0, stream>>>(wq, wqkvT, HIDW, KOFF);
  k_tr_cvt<<<dim3((NKVH * HD) / 32, HIDW / 32), 256, 0, stream>>>(
      wk, wqkvT + (size_t)KOFF * HIDW, HIDW, NKVH * HD);
  k_tr_cvt<<<dim3((NKVH * HD) / 32, HIDW / 32), 256, 0, stream>>>(
      wv, wqkvT + (size_t)VOFF * HIDW, HIDW, NKVH * HD);
  k_tr_cvt<<<dim3(HIDW / 32, KOFF / 32), 256, 0, stream>>>(wo, woT, KOFF, HIDW);
  // 3) QKV projection (R13 best-measured: 256x256, 192 blocks) + fused rope
  k_gemm256<2, 2><<<(MROWS / 256) * (QKVN / 256), 512, 0, stream>>>(
      xb, wqkvT, qkv, MROWS, QKVN, HIDW, QKVN / 256, cosT, sinT);
  // 4) V transpose
  k_vt<<<dim3(S_LEN / 32, 4 * NKVH, NB), 256, 0, stream>>>(qkv, vtb);
  // 5) attention: 512 blocks x 4 waves, 2 q-subtiles/wave (ctx -> xb)
  k_attn<<<32 * 16, 256, 0, stream>>>(qkv, vtb, xb);
  // 6) output projection -> f32 d_out (128x256 tile, 256 blocks = 100% fill)
  k_gemm256<0, 1><<<(MROWS / 128) * (HIDW / 256), 512, 0, stream>>>(
      xb, woT, d_out, MROWS, HIDW, KOFF, HIDW / 256, nullptr, nullptr);
}

// Round 19
// 205.650 us; speedup vs baseline: 1.0414x; 1.0414x over previous
//
#include <hip/hip_runtime.h>
#include <hip/hip_bf16.h>
#include <math.h>

#define S_LEN 2048
#define HIDW 2048
#define NHEAD 16
#define NKVH 4
#define HD 128
#define NB 2
#define MROWS (NB * S_LEN)                 // 4096
#define QKVN (NHEAD * HD + 2 * NKVH * HD)  // 3072
#define KOFF (NHEAD * HD)                  // 2048
#define VOFF (NHEAD * HD + NKVH * HD)      // 2560

typedef __bf16 bf16_t;
typedef __bf16 bf16x8_t __attribute__((ext_vector_type(8)));
typedef float f32x4_t __attribute__((ext_vector_type(4)));

__device__ __forceinline__ void gload_lds16(const bf16_t* g, bf16_t* l) {
  __builtin_amdgcn_global_load_lds(
      (const __attribute__((address_space(1))) void*)g,
      (__attribute__((address_space(3))) void*)l, 16, 0, 0);
}

__device__ __forceinline__ f32x4_t zero4() {
  f32x4_t z = {0.f, 0.f, 0.f, 0.f};
  return z;
}

__device__ __forceinline__ float fexp2(float x) {
#if __has_builtin(__builtin_amdgcn_exp2f)
  return __builtin_amdgcn_exp2f(x);
#else
  return exp2f(x);
#endif
}

// ---------------- convert x (f32 -> bf16), 8 elems/thread ----------------
__global__ __launch_bounds__(256) void k_cvt8(const float* __restrict__ in,
                                              bf16_t* __restrict__ out, int n8) {
  int i = blockIdx.x * 256 + threadIdx.x;
  if (i >= n8) return;
  const float4* p = (const float4*)(in + (size_t)i * 8);
  float4 a = p[0], b = p[1];
  bf16x8_t r;
  r[0] = (bf16_t)a.x; r[1] = (bf16_t)a.y; r[2] = (bf16_t)a.z; r[3] = (bf16_t)a.w;
  r[4] = (bf16_t)b.x; r[5] = (bf16_t)b.y; r[6] = (bf16_t)b.z; r[7] = (bf16_t)b.w;
  *(bf16x8_t*)(out + (size_t)i * 8) = r;
}

// ---------------- transpose + convert: in f32 [R][C] -> out bf16 [C][R] ----
__global__ __launch_bounds__(256) void k_tr_cvt(const float* __restrict__ in,
                                                bf16_t* __restrict__ out, int R, int C) {
  __shared__ float t[32][33];
  int c0 = blockIdx.x * 32, r0 = blockIdx.y * 32;
  int tx = threadIdx.x & 31, ty = threadIdx.x >> 5;
#pragma unroll
  for (int rr = ty; rr < 32; rr += 8) t[rr][tx] = in[(size_t)(r0 + rr) * C + c0 + tx];
  __syncthreads();
#pragma unroll
  for (int rr = ty; rr < 32; rr += 8)
    out[(size_t)(c0 + rr) * R + r0 + tx] = (bf16_t)t[tx][rr];
}

// ---- QKV GEMM: 256x256, m201 8-phase port (2 barriers/phase, per-phase ----
// half-tile staging, boundary counted vmcnt). LDS: A/B each [2 buf][2 half
// x 128row x 64K] = 128 KB. Per K-tile, 4 phases x {ds_reads; stage 1 half;
// BAR; lgkmcnt(0); sched_barrier; setprio(1); 16 MFMA; setprio(0); BAR}.
// Reads: af0+b01@P0, b23@P1, af1@P2. Stages (slot free >= 1 barrier before):
// A1(t+1)@P0, B0(t+2)@P2, A0(t+2)+B1(t+2)@P3. Boundary vmcnt(10): all 4
// halves of t+1 landed (oldest 4 of 14 outstanding); vmcnt(0) last 2 tiles.
// Fused rope epilogue (cos/sin staged in dead LDS) unchanged from R13.
__global__ __launch_bounds__(512, 2) void k_gemm_qkv8(const bf16_t* __restrict__ A,
                                                      const bf16_t* __restrict__ Bt,
                                                      bf16_t* __restrict__ qkv,
                                                      const float* __restrict__ cosT,
                                                      const float* __restrict__ sinT) {
  __shared__ bf16_t As[2][16384];  // [buf][half*8192 + row*64 + col]
  __shared__ bf16_t Bs[2][16384];
  const int K = HIDW, N = QKVN;
  int tid = threadIdx.x;
  int lane = tid & 63, wid = tid >> 6;
  int l15 = lane & 15, lg = lane >> 4;
  int wrb = (wid >> 2) * 128;   // wave M-offset
  int wcb = (wid & 3) * 64;     // wave N-offset
  int ah = wid >> 2;            // A LDS half this wave reads
  int bh2 = wcb >> 7;           // B LDS half this wave reads
  int brow0 = wcb & 64;         // row offset within B half

  int qx = gridDim.x >> 3;
  int lin = blockIdx.x;
  int wg = (lin & 7) * qx + (lin >> 3);
  int row0 = (wg / 12) * 256, col0 = (wg % 12) * 256;

  int srow = tid >> 3;
  int scol = ((tid & 7) ^ (srow & 7)) * 8;
  const bf16_t* Ag = A + (size_t)(row0 + srow) * K + scol;
  const bf16_t* Bg = Bt + (size_t)(col0 + srow) * K + scol;

  f32x4_t acc[8][4];
#pragma unroll
  for (int i = 0; i < 8; i++)
#pragma unroll
    for (int j = 0; j < 4; j++) acc[i][j] = zero4();

  int xr = (l15 & 7) << 4;
  const int nk = K >> 6;  // 32

  auto stA = [&](int tt, int h, int u) {
    gload_lds16(Ag + (size_t)(h * 128 + u * 64) * K + (size_t)tt * 64,
                As[tt & 1] + h * 8192 + u * 4096 + tid * 8);
  };
  auto stB = [&](int tt, int h, int u) {
    gload_lds16(Bg + (size_t)(h * 128 + u * 64) * K + (size_t)tt * 64,
                Bs[tt & 1] + h * 8192 + u * 4096 + tid * 8);
  };

  // prologue: issue order B0(0),A0(0),B1(0),A1(0),B0(1),A0(1),B1(1)
  stB(0, 0, 0); stB(0, 0, 1); stA(0, 0, 0); stA(0, 0, 1);
  stB(0, 1, 0); stB(0, 1, 1); stA(0, 1, 0); stA(0, 1, 1);
  stB(1, 0, 0); stB(1, 0, 1); stA(1, 0, 0); stA(1, 0, 1);
  stB(1, 1, 0); stB(1, 1, 1);
  asm volatile("s_waitcnt vmcnt(10)" ::: "memory");
  __builtin_amdgcn_s_barrier();
  __builtin_amdgcn_sched_barrier(0);

  for (int t = 0; t < nk; t++) {
    const char* Ac = (const char*)As[t & 1] + ah * 16384;
    const char* Bc = (const char*)Bs[t & 1] + bh2 * 16384;

    // ---- P0: reads af0(8) + b01(4); stage A1(t+1) ----
    bf16x8_t af0[4][2], bfr[4][2];
#pragma unroll
    for (int i = 0; i < 4; i++) {
      int row = i * 16 + l15;
#pragma unroll
      for (int kk = 0; kk < 2; kk++)
        af0[i][kk] = *(const bf16x8_t*)(Ac + ((row * 128 + kk * 64 + lg * 16) ^ xr));
    }
#pragma unroll
    for (int j = 0; j < 2; j++) {
      int row = brow0 + j * 16 + l15;
#pragma unroll
      for (int kk = 0; kk < 2; kk++)
        bfr[j][kk] = *(const bf16x8_t*)(Bc + ((row * 128 + kk * 64 + lg * 16) ^ xr));
    }
    if (t + 1 < nk) { stA(t + 1, 1, 0); stA(t + 1, 1, 1); }
    __builtin_amdgcn_s_barrier();
    asm volatile("s_waitcnt lgkmcnt(0)" ::: "memory");
    __builtin_amdgcn_sched_barrier(0);
    __builtin_amdgcn_s_setprio(1);
#pragma unroll
    for (int i = 0; i < 4; i++)
#pragma unroll
      for (int j = 0; j < 2; j++)
#pragma unroll
        for (int kk = 0; kk < 2; kk++)
          acc[i][j] = __builtin_amdgcn_mfma_f32_16x16x32_bf16(af0[i][kk], bfr[j][kk],
                                                              acc[i][j], 0, 0, 0);
    __builtin_amdgcn_s_setprio(0);
    __builtin_amdgcn_s_barrier();

    // ---- P1: reads b23(4) ----
#pragma unroll
    for (int j = 2; j < 4; j++) {
      int row = brow0 + j * 16 + l15;
#pragma unroll
      for (int kk = 0; kk < 2; kk++)
        bfr[j][kk] = *(const bf16x8_t*)(Bc + ((row * 128 + kk * 64 + lg * 16) ^ xr));
    }
    __builtin_amdgcn_s_barrier();
    asm volatile("s_waitcnt lgkmcnt(0)" ::: "memory");
    __builtin_amdgcn_sched_barrier(0);
    __builtin_amdgcn_s_setprio(1);
#pragma unroll
    for (int i = 0; i < 4; i++)
#pragma unroll
      for (int j = 2; j < 4; j++)
#pragma unroll
        for (int kk = 0; kk < 2; kk++)
          acc[i][j] = __builtin_amdgcn_mfma_f32_16x16x32_bf16(af0[i][kk], bfr[j][kk],
                                                              acc[i][j], 0, 0, 0);
    __builtin_amdgcn_s_setprio(0);
    __builtin_amdgcn_s_barrier();

    // ---- P2: reads af1(8); stage B0(t+2) ----
    bf16x8_t af1[4][2];
#pragma unroll
    for (int i = 0; i < 4; i++) {
      int row = 64 + i * 16 + l15;
#pragma unroll
      for (int kk = 0; kk < 2; kk++)
        af1[i][kk] = *(const bf16x8_t*)(Ac + ((row * 128 + kk * 64 + lg * 16) ^ xr));
    }
    if (t + 2 < nk) { stB(t + 2, 0, 0); stB(t + 2, 0, 1); }
    __builtin_amdgcn_s_barrier();
    asm volatile("s_waitcnt lgkmcnt(0)" ::: "memory");
    __builtin_amdgcn_sched_barrier(0);
    __builtin_amdgcn_s_setprio(1);
#pragma unroll
    for (int i = 0; i < 4; i++)
#pragma unroll
      for (int j = 0; j < 2; j++)
#pragma unroll
        for (int kk = 0; kk < 2; kk++)
          acc[4 + i][j] = __builtin_amdgcn_mfma_f32_16x16x32_bf16(
              af1[i][kk], bfr[j][kk], acc[4 + i][j], 0, 0, 0);
    __builtin_amdgcn_s_setprio(0);
    __builtin_amdgcn_s_barrier();

    // ---- P3: stage A0(t+2) + B1(t+2); MFMA; boundary vmcnt ----
    if (t + 2 < nk) { stA(t + 2, 0, 0); stA(t + 2, 0, 1); stB(t + 2, 1, 0); stB(t + 2, 1, 1); }
    __builtin_amdgcn_s_barrier();
    __builtin_amdgcn_s_setprio(1);
#pragma unroll
    for (int i = 0; i < 4; i++)
#pragma unroll
      for (int j = 2; j < 4; j++)
#pragma unroll
        for (int kk = 0; kk < 2; kk++)
          acc[4 + i][j] = __builtin_amdgcn_mfma_f32_16x16x32_bf16(
              af1[i][kk], bfr[j][kk], acc[4 + i][j], 0, 0, 0);
    __builtin_amdgcn_s_setprio(0);
    if (t + 2 < nk) asm volatile("s_waitcnt vmcnt(10)" ::: "memory");
    else            asm volatile("s_waitcnt vmcnt(0)" ::: "memory");
    __builtin_amdgcn_s_barrier();
    __builtin_amdgcn_sched_barrier(0);
  }

  // ---- fused rope epilogue (R13-verified) ----
  if (col0 < VOFF) {
    int sbase = row0 & (S_LEN - 1);
    bf16_t* cosL = &As[0][0];
    bf16_t* sinL = &Bs[0][0];
#pragma unroll
    for (int k = 0; k < 8; k++) {
      gload_lds16((const bf16_t*)(cosT + (size_t)sbase * 64 + k * 2048 + tid * 4),
                  cosL + k * 4096 + tid * 8);
      gload_lds16((const bf16_t*)(sinT + (size_t)sbase * 64 + k * 2048 + tid * 4),
                  sinL + k * 4096 + tid * 8);
    }
    asm volatile("s_waitcnt vmcnt(0)" ::: "memory");
    __builtin_amdgcn_s_barrier();
    const float* cosF = (const float*)cosL;
    const float* sinF = (const float*)sinL;
    const float QS = 0.08838834764831845f * 1.4426950408889634f;
#pragma unroll
    for (int i = 0; i < 8; i++) {
#pragma unroll
      for (int j = 0; j < 4; j++) {
        int c = col0 + wcb + j * 16 + l15;
        int rlb = wrb + ((i < 4) ? i * 16 : 64 + (i - 4) * 16) + lg * 4;
        float scale = (c < KOFF) ? QS : 1.0f;
        int p0 = (c & 127) >> 1;
        int codd = c & 1;
#pragma unroll
        for (int qd = 0; qd < 4; qd++) {
          int rl = rlb + qd;
          float self = acc[i][j][qd];
          float other = __shfl_xor(self, 1);
          float cv = cosF[rl * 64 + p0], sv = sinF[rl * 64 + p0];
          float outv = codd ? (self * cv + other * sv) : (self * cv - other * sv);
          ((bf16_t*)qkv)[(size_t)(row0 + rl) * N + c] = (bf16_t)(outv * scale);
        }
      }
    }
  } else {
#pragma unroll
    for (int i = 0; i < 8; i++) {
#pragma unroll
      for (int j = 0; j < 4; j++) {
        int r = row0 + wrb + ((i < 4) ? i * 16 : 64 + (i - 4) * 16) + lg * 4;
        int c = col0 + wcb + j * 16 + l15;
#pragma unroll
        for (int qd = 0; qd < 4; qd++)
          qkv[(size_t)(r + qd) * N + c] = (bf16_t)acc[i][j][qd];
      }
    }
  }
}

// ------------- out-proj GEMM: 128x256 tile (R13 counted schedule) ----------
__global__ __launch_bounds__(512, 2) void k_gemm_out(const bf16_t* __restrict__ A,
                                                     const bf16_t* __restrict__ Bt,
                                                     float* __restrict__ Cout) {
  __shared__ bf16_t As[2][128 * 64];
  __shared__ bf16_t Bs[2][256 * 64];
  const int K = KOFF, N = HIDW;
  int tid = threadIdx.x;
  int lane = tid & 63, wid = tid >> 6;
  int l15 = lane & 15, lg = lane >> 4;
  int wrb = (wid >> 2) * 64;
  int wcb = (wid & 3) * 64;

  int qx = gridDim.x >> 3;
  int lin = blockIdx.x;
  int wg = (lin & 7) * qx + (lin >> 3);
  int row0 = (wg >> 3) * 128, col0 = (wg & 7) * 256;

  int srow = tid >> 3;
  int scol = ((tid & 7) ^ (srow & 7)) * 8;
  const bf16_t* Ag = A + (size_t)(row0 + srow) * K + scol;
  const bf16_t* Bg = Bt + (size_t)(col0 + srow) * K + scol;

  f32x4_t acc[4][4];
#pragma unroll
  for (int i = 0; i < 4; i++)
#pragma unroll
    for (int j = 0; j < 4; j++) acc[i][j] = zero4();

  int xr = (l15 & 7) << 4;
  const int nk = K >> 6;

  auto stA = [&](int tt, int u) {
    gload_lds16(Ag + (size_t)u * 64 * K + (size_t)tt * 64, As[tt & 1] + u * 4096 + tid * 8);
  };
  auto stB = [&](int tt, int u) {
    gload_lds16(Bg + (size_t)u * 64 * K + (size_t)tt * 64, Bs[tt & 1] + u * 4096 + tid * 8);
  };

  for (int tt = 0; tt < 2; tt++) {
    for (int u = 0; u < 2; u++) stA(tt, u);
    for (int u = 0; u < 4; u++) stB(tt, u);
  }
  asm volatile("s_waitcnt vmcnt(6)" ::: "memory");
  __builtin_amdgcn_s_barrier();
  __builtin_amdgcn_sched_barrier(0);

  for (int t = 0; t < nk; t++) {
    const char* Ac = (const char*)As[t & 1];
    const char* Bc = (const char*)Bs[t & 1];
    bool pf = (t + 2 < nk);

    bf16x8_t af0[4][2], bfr[4][2];
#pragma unroll
    for (int i = 0; i < 4; i++) {
      int row = wrb + i * 16 + l15;
#pragma unroll
      for (int kk = 0; kk < 2; kk++)
        af0[i][kk] = *(const bf16x8_t*)(Ac + ((row * 128 + kk * 64 + lg * 16) ^ xr));
    }
#pragma unroll
    for (int j = 0; j < 4; j++) {
      int rowb = wcb + j * 16 + l15;
#pragma unroll
      for (int kk = 0; kk < 2; kk++)
        bfr[j][kk] = *(const bf16x8_t*)(Bc + ((rowb * 128 + kk * 64 + lg * 16) ^ xr));
    }
    __builtin_amdgcn_s_barrier();
    __builtin_amdgcn_s_setprio(1);
#pragma unroll
    for (int i = 0; i < 4; i++)
#pragma unroll
      for (int kk = 0; kk < 2; kk++)
        acc[i][0] = __builtin_amdgcn_mfma_f32_16x16x32_bf16(af0[i][kk], bfr[0][kk],
                                                            acc[i][0], 0, 0, 0);
    __builtin_amdgcn_s_setprio(0);

    if (pf) { stA(t + 2, 0); stA(t + 2, 1); }
    __builtin_amdgcn_s_barrier();
    __builtin_amdgcn_s_setprio(1);
#pragma unroll
    for (int i = 0; i < 4; i++)
#pragma unroll
      for (int kk = 0; kk < 2; kk++)
        acc[i][1] = __builtin_amdgcn_mfma_f32_16x16x32_bf16(af0[i][kk], bfr[1][kk],
                                                            acc[i][1], 0, 0, 0);
    __builtin_amdgcn_s_setprio(0);

    if (pf) { stB(t + 2, 0); stB(t + 2, 1); }
    __builtin_amdgcn_s_barrier();
    __builtin_amdgcn_s_setprio(1);
#pragma unroll
    for (int i = 0; i < 4; i++)
#pragma unroll
      for (int kk = 0; kk < 2; kk++)
        acc[i][2] = __builtin_amdgcn_mfma_f32_16x16x32_bf16(af0[i][kk], bfr[2][kk],
                                                            acc[i][2], 0, 0, 0);
    __builtin_amdgcn_s_setprio(0);

    if (pf) { stB(t + 2, 2); stB(t + 2, 3); }
    __builtin_amdgcn_s_barrier();
    __builtin_amdgcn_s_setprio(1);
#pragma unroll
    for (int i = 0; i < 4; i++)
#pragma unroll
      for (int kk = 0; kk < 2; kk++)
        acc[i][3] = __builtin_amdgcn_mfma_f32_16x16x32_bf16(af0[i][kk], bfr[3][kk],
                                                            acc[i][3], 0, 0, 0);
    __builtin_amdgcn_s_setprio(0);

    if (t + 1 < nk) {
      if (pf) asm volatile("s_waitcnt vmcnt(6)" ::: "memory");
      else    asm volatile("s_waitcnt vmcnt(0)" ::: "memory");
    }
    __builtin_amdgcn_s_barrier();
    __builtin_amdgcn_sched_barrier(0);
  }

#pragma unroll
  for (int i = 0; i < 4; i++) {
#pragma unroll
    for (int j = 0; j < 4; j++) {
      int r = row0 + wrb + i * 16 + lg * 4;
      int c = col0 + wcb + j * 16 + l15;
#pragma unroll
      for (int qd = 0; qd < 4; qd++)
        Cout[(size_t)(r + qd) * N + c] = acc[i][j][qd];
    }
  }
}

// ---------------- V -> Vt relayout: vt[b][kvh][d][s] -----------------------
__global__ __launch_bounds__(256) void k_vt(const bf16_t* __restrict__ qkv,
                                            bf16_t* __restrict__ vt) {
  __shared__ bf16_t t[32][33];
  int s0 = blockIdx.x * 32;
  int dt = (blockIdx.y & 3) * 32;
  int h = blockIdx.y >> 2;
  int b = blockIdx.z;
  int tx = threadIdx.x & 31, ty = threadIdx.x >> 5;
#pragma unroll
  for (int rr = ty; rr < 32; rr += 8)
    t[rr][tx] = qkv[(size_t)(b * S_LEN + s0 + rr) * QKVN + VOFF + h * HD + dt + tx];
  __syncthreads();
#pragma unroll
  for (int rr = ty; rr < 32; rr += 8)
    vt[((size_t)((b * NKVH + h) * HD + dt + rr)) * S_LEN + s0 + tx] = t[tx][rr];
}

// ---------------- flash attention: 4 waves, QBLK=64 (R12/R13 verified) -----
__global__ __launch_bounds__(256, 2) void k_attn(const bf16_t* __restrict__ qkv,
                                                 const bf16_t* __restrict__ vt,
                                                 bf16_t* __restrict__ ctx) {
  __shared__ bf16_t Ks[2 * 64 * 128];
  __shared__ bf16_t Vs[2 * 128 * 64];
  __shared__ bf16_t plds[4][16 * 72];

  int tid = threadIdx.x;
  int lane = tid & 63, wid = tid >> 6;
  int idx = blockIdx.x;
  int bh = idx & 31;
  int qg = 31 - (idx >> 5);
  int b = bh >> 4, h = bh & 15;
  int kvh = h >> 2;
  int q0 = qg * 64 + wid * 16;
  int l15 = lane & 15, lg = lane >> 4;

  const bf16_t* Kbase = qkv + (size_t)(b * S_LEN) * QKVN + KOFF + kvh * HD;
  const bf16_t* Vbase = vt + (size_t)(b * NKVH + kvh) * HD * S_LEN;

  const bf16_t* Qp = qkv + (size_t)(b * S_LEN + q0 + l15) * QKVN + h * HD + lg * 8;
  bf16x8_t aq[4];
#pragma unroll
  for (int kk = 0; kk < 4; kk++) aq[kk] = *(const bf16x8_t*)(Qp + kk * 32);

  int Ls[4], Lk[4], Lv[4];
#pragma unroll
  for (int u = 0; u < 4; u++) {
    int L = u * 4096 + tid * 16;
    Ls[u] = L >> 1;
    Lk[u] = L ^ (((L >> 8) & 7) << 4);
    Lv[u] = L ^ (((L >> 7) & 7) << 4);
  }

  f32x4_t o[8];
#pragma unroll
  for (int j = 0; j < 8; j++) o[j] = zero4();
  float ms = -INFINITY, lsum = 0.f;

  bf16_t* pbuf = &plds[wid][0];
  int xr = (l15 & 7) << 4;
  int ntiles = qg + 1;
  int qcol = q0 + l15;

#pragma unroll
  for (int u = 0; u < 4; u++) {
    gload_lds16(Kbase + (size_t)(Lk[u] >> 8) * QKVN + ((Lk[u] & 255) >> 1), Ks + Ls[u]);
    gload_lds16(Vbase + (size_t)(Lv[u] >> 7) * S_LEN + ((Lv[u] & 127) >> 1), Vs + Ls[u]);
  }
  __syncthreads();

  for (int t = 0; t < ntiles; t++) {
    int kv0 = t * 64;
    if (t + 1 < ntiles) {
      const bf16_t* Kn = Kbase + (size_t)(kv0 + 64) * QKVN;
      const bf16_t* Vn = Vbase + kv0 + 64;
      int bo = ((t + 1) & 1) * 8192;
#pragma unroll
      for (int u = 0; u < 4; u++) {
        gload_lds16(Kn + (size_t)(Lk[u] >> 8) * QKVN + ((Lk[u] & 255) >> 1), Ks + bo + Ls[u]);
        gload_lds16(Vn + (size_t)(Lv[u] >> 7) * S_LEN + ((Lv[u] & 127) >> 1), Vs + bo + Ls[u]);
      }
    }
    const char* Kb = (const char*)Ks + (t & 1) * 16384;
    const char* Vb = (const char*)Vs + (t & 1) * 16384;

    f32x4_t sacc[4];
#pragma unroll
    for (int cg = 0; cg < 4; cg++) sacc[cg] = zero4();
#pragma unroll
    for (int cg = 0; cg < 4; cg++) {
#pragma unroll
      for (int kk = 0; kk < 4; kk++) {
        int boff = ((cg * 16 + l15) * 256 + kk * 64 + lg * 16) ^ xr;
        bf16x8_t bk = *(const bf16x8_t*)(Kb + boff);
        sacc[cg] = __builtin_amdgcn_mfma_f32_16x16x32_bf16(bk, aq[kk], sacc[cg], 0, 0, 0);
      }
    }
    if (kv0 + 63 > q0) {
#pragma unroll
      for (int cg = 0; cg < 4; cg++) {
#pragma unroll
        for (int i = 0; i < 4; i++) {
          int kvg = kv0 + cg * 16 + lg * 4 + i;
          if (kvg > qcol) sacc[cg][i] = -1e30f;
        }
      }
    }
    float pmax = sacc[0][0];
#pragma unroll
    for (int cg = 0; cg < 4; cg++)
#pragma unroll
      for (int i = 0; i < 4; i++) pmax = fmaxf(pmax, sacc[cg][i]);
    pmax = fmaxf(pmax, __shfl_xor(pmax, 16));
    pmax = fmaxf(pmax, __shfl_xor(pmax, 32));
    if (__any(pmax - ms > 8.0f)) {
      float nm = fmaxf(ms, pmax);
      float sc = fexp2(ms - nm);
      ms = nm;
      lsum *= sc;
      float sci[4];
#pragma unroll
      for (int i = 0; i < 4; i++) sci[i] = __shfl(sc, lg * 4 + i);
#pragma unroll
      for (int j = 0; j < 8; j++)
#pragma unroll
        for (int i = 0; i < 4; i++) o[j][i] *= sci[i];
    }
    float ls = 0.f;
#pragma unroll
    for (int cg = 0; cg < 4; cg++)
#pragma unroll
      for (int i = 0; i < 4; i++) {
        sacc[cg][i] = fexp2(sacc[cg][i] - ms);
        ls += sacc[cg][i];
      }
    ls += __shfl_xor(ls, 16);
    ls += __shfl_xor(ls, 32);
    lsum += ls;
#pragma unroll
    for (int cg = 0; cg < 4; cg++)
#pragma unroll
      for (int i = 0; i < 4; i++)
        pbuf[l15 * 72 + cg * 16 + lg * 4 + i] = (bf16_t)sacc[cg][i];
    __builtin_amdgcn_wave_barrier();
    bf16x8_t pa0 = *(const bf16x8_t*)(pbuf + l15 * 72 + lg * 8);
    bf16x8_t pa1 = *(const bf16x8_t*)(pbuf + l15 * 72 + 32 + lg * 8);
    __builtin_amdgcn_wave_barrier();
#pragma unroll
    for (int j = 0; j < 8; j++) {
      int d = j * 16 + l15;
      int bo0 = (d * 128 + lg * 16) ^ xr;
      int bo1 = (d * 128 + 64 + lg * 16) ^ xr;
      o[j] = __builtin_amdgcn_mfma_f32_16x16x32_bf16(
          pa0, *(const bf16x8_t*)(Vb + bo0), o[j], 0, 0, 0);
      o[j] = __builtin_amdgcn_mfma_f32_16x16x32_bf16(
          pa1, *(const bf16x8_t*)(Vb + bo1), o[j], 0, 0, 0);
    }
    __syncthreads();
  }

  bf16_t* Cp = ctx + (size_t)(b * S_LEN + q0) * KOFF + h * HD;
#pragma unroll
  for (int i = 0; i < 4; i++) {
    float inv = 1.f / __shfl(lsum, lg * 4 + i);
    int row = lg * 4 + i;
#pragma unroll
    for (int j = 0; j < 8; j++)
      Cp[(size_t)row * KOFF + j * 16 + l15] = (bf16_t)(o[j][i] * inv);
  }
}

extern "C" void kernel_launch(void* const* d_in, const int* in_sizes, int n_in,
                              void* d_out, int out_size, void* d_ws, size_t ws_size,
                              hipStream_t stream) {
  const float* x = (const float*)d_in[0];
  const float* wq = (const float*)d_in[1];
  const float* wk = (const float*)d_in[2];
  const float* wv = (const float*)d_in[3];
  const float* wo = (const float*)d_in[4];
  const float* cosT = (const float*)d_in[5];
  const float* sinT = (const float*)d_in[6];

  bf16_t* xb = (bf16_t*)d_ws;                          // 4096x2048 (later reused as ctx)
  bf16_t* wqkvT = xb + (size_t)MROWS * HIDW;           // 3072x2048
  bf16_t* woT = wqkvT + (size_t)QKVN * HIDW;           // 2048x2048
  bf16_t* qkv = woT + (size_t)HIDW * HIDW;             // 4096x3072
  bf16_t* vtb = qkv + (size_t)MROWS * QKVN;            // 2*4*128*2048

  // 1) convert x
  k_cvt8<<<MROWS * HIDW / 8 / 256, 256, 0, stream>>>(x, xb, MROWS * HIDW / 8);
  // 2) weight transposes (f32 -> bf16, [K][N] -> [N][K])
  k_tr_cvt<<<dim3(KOFF / 32, HIDW / 32), 256, 0, stream>>>(wq, wqkvT, HIDW, KOFF);
  k_tr_cvt<<<dim3((NKVH * HD) / 32, HIDW / 32), 256, 0, stream>>>(
      wk, wqkvT + (size_t)KOFF * HIDW, HIDW, NKVH * HD);
  k_tr_cvt<<<dim3((NKVH * HD) / 32, HIDW / 32), 256, 0, stream>>>(
      wv, wqkvT + (size_t)VOFF * HIDW, HIDW, NKVH * HD);
  k_tr_cvt<<<dim3(HIDW / 32, KOFF / 32), 256, 0, stream>>>(wo, woT, KOFF, HIDW);
  // 3) QKV projection: m201 8-phase port + fused rope
  k_gemm_qkv8<<<(MROWS / 256) * (QKVN / 256), 512, 0, stream>>>(
      xb, wqkvT, qkv, cosT, sinT);
  // 4) V transpose
  k_vt<<<dim3(S_LEN / 32, 4 * NKVH, NB), 256, 0, stream>>>(qkv, vtb);
  // 5) attention (R12/R13-verified; ctx -> xb region)
  k_attn<<<32 * 32, 256, 0, stream>>>(qkv, vtb, xb);
  // 6) output projection -> f32 d_out
  k_gemm_out<<<(MROWS / 128) * (HIDW / 256), 512, 0, stream>>>(xb, woT,
                                                               (float*)d_out);
}

// Round 20
// 189.988 us; speedup vs baseline: 1.1273x; 1.0824x over previous
//
#include <hip/hip_runtime.h>
#include <hip/hip_bf16.h>
#include <math.h>

#define S_LEN 2048
#define HIDW 2048
#define NHEAD 16
#define NKVH 4
#define HD 128
#define NB 2
#define MROWS (NB * S_LEN)                 // 4096
#define QKVN (NHEAD * HD + 2 * NKVH * HD)  // 3072
#define KOFF (NHEAD * HD)                  // 2048
#define VOFF (NHEAD * HD + NKVH * HD)      // 2560

typedef __bf16 bf16_t;
typedef __bf16 bf16x8_t __attribute__((ext_vector_type(8)));
typedef float f32x4_t __attribute__((ext_vector_type(4)));

__device__ __forceinline__ void gload_lds16(const bf16_t* g, bf16_t* l) {
  __builtin_amdgcn_global_load_lds(
      (const __attribute__((address_space(1))) void*)g,
      (__attribute__((address_space(3))) void*)l, 16, 0, 0);
}

__device__ __forceinline__ f32x4_t zero4() {
  f32x4_t z = {0.f, 0.f, 0.f, 0.f};
  return z;
}

__device__ __forceinline__ float fexp2(float x) {
#if __has_builtin(__builtin_amdgcn_exp2f)
  return __builtin_amdgcn_exp2f(x);
#else
  return exp2f(x);
#endif
}

// ---------------- convert x (f32 -> bf16), 8 elems/thread ----------------
__global__ __launch_bounds__(256) void k_cvt8(const float* __restrict__ in,
                                              bf16_t* __restrict__ out, int n8) {
  int i = blockIdx.x * 256 + threadIdx.x;
  if (i >= n8) return;
  const float4* p = (const float4*)(in + (size_t)i * 8);
  float4 a = p[0], b = p[1];
  bf16x8_t r;
  r[0] = (bf16_t)a.x; r[1] = (bf16_t)a.y; r[2] = (bf16_t)a.z; r[3] = (bf16_t)a.w;
  r[4] = (bf16_t)b.x; r[5] = (bf16_t)b.y; r[6] = (bf16_t)b.z; r[7] = (bf16_t)b.w;
  *(bf16x8_t*)(out + (size_t)i * 8) = r;
}

// ---------------- transpose + convert: in f32 [R][C] -> out bf16 [C][R] ----
__global__ __launch_bounds__(256) void k_tr_cvt(const float* __restrict__ in,
                                                bf16_t* __restrict__ out, int R, int C) {
  __shared__ float t[32][33];
  int c0 = blockIdx.x * 32, r0 = blockIdx.y * 32;
  int tx = threadIdx.x & 31, ty = threadIdx.x >> 5;
#pragma unroll
  for (int rr = ty; rr < 32; rr += 8) t[rr][tx] = in[(size_t)(r0 + rr) * C + c0 + tx];
  __syncthreads();
#pragma unroll
  for (int rr = ty; rr < 32; rr += 8)
    out[(size_t)(c0 + rr) * R + r0 + tx] = (bf16_t)t[tx][rr];
}

// ------- merged QKV weight transpose: wq|wk|wv -> wqkvT [3072][2048] -------
// Output row n: n<2048 -> wq col n (C=2048); n<2560 -> wk col n-2048 (C=512);
// else wv col n-2560 (C=512). Regions are 32-aligned -> block-uniform select.
__global__ __launch_bounds__(256) void k_tr_qkvw(const float* __restrict__ wq,
                                                 const float* __restrict__ wk,
                                                 const float* __restrict__ wv,
                                                 bf16_t* __restrict__ out) {
  __shared__ float t[32][33];
  int c0 = blockIdx.x * 32, r0 = blockIdx.y * 32;  // c0 = output row base
  const float* src;
  int C, cb;
  if (c0 < KOFF)      { src = wq; C = 2048; cb = c0; }
  else if (c0 < VOFF) { src = wk; C = 512;  cb = c0 - KOFF; }
  else                { src = wv; C = 512;  cb = c0 - VOFF; }
  int tx = threadIdx.x & 31, ty = threadIdx.x >> 5;
#pragma unroll
  for (int rr = ty; rr < 32; rr += 8) t[rr][tx] = src[(size_t)(r0 + rr) * C + cb + tx];
  __syncthreads();
#pragma unroll
  for (int rr = ty; rr < 32; rr += 8)
    out[(size_t)(c0 + rr) * HIDW + r0 + tx] = (bf16_t)t[tx][rr];
}

// ---------------- GEMM BMx256 tile (BM = BMH*128), BK=64, 8 waves ----------
// R13 counted-vmcnt 4-phase schedule — best measured of 7 variants (94 us;
// drain-0 / free-run / 100%-fill-thin / m201-8-phase all 94-110 us at ~20%
// MfmaUtil: per-shape ceiling of this structure family at K=2048).
// EPI=0: f32 out. EPI=2: fused rope epilogue (cos/sin staged in dead LDS).
template <int EPI, int BMH>
__global__ __launch_bounds__(512, 2) void k_gemm256(const bf16_t* __restrict__ A,
                                                    const bf16_t* __restrict__ Bt,
                                                    void* __restrict__ Cout,
                                                    int M, int N, int K, int nby,
                                                    const float* __restrict__ cosT,
                                                    const float* __restrict__ sinT) {
  __shared__ bf16_t As[2][BMH * 128 * 64];
  __shared__ bf16_t Bs[2][256 * 64];

  int tid = threadIdx.x;
  int lane = tid & 63, wid = tid >> 6;
  int l15 = lane & 15, lg = lane >> 4;
  int wrb = (wid >> 2) * (BMH * 64);
  int wcb = (wid & 3) * 64;

  int nwg = gridDim.x;
  int qx = nwg >> 3;
  int lin = blockIdx.x;
  int wg = (lin & 7) * qx + (lin >> 3);
  int row0 = (wg / nby) * (BMH * 128), col0 = (wg % nby) * 256;

  int srow = tid >> 3;
  int scol = ((tid & 7) ^ (srow & 7)) * 8;
  const bf16_t* Ag = A + (size_t)(row0 + srow) * K + scol;
  const bf16_t* Bg = Bt + (size_t)(col0 + srow) * K + scol;

  f32x4_t acc[BMH * 4][4];
#pragma unroll
  for (int i = 0; i < BMH * 4; i++)
#pragma unroll
    for (int j = 0; j < 4; j++) acc[i][j] = zero4();

  int xr = (l15 & 7) << 4;
  int nk = K >> 6;

  auto stA = [&](int tt, int u) {
    gload_lds16(Ag + (size_t)u * 64 * K + (size_t)tt * 64,
                As[tt & 1] + u * 4096 + tid * 8);
  };
  auto stB = [&](int tt, int u) {
    gload_lds16(Bg + (size_t)u * 64 * K + (size_t)tt * 64,
                Bs[tt & 1] + u * 4096 + tid * 8);
  };

  for (int tt = 0; tt < 2 && tt < nk; tt++) {
    for (int u = 0; u < BMH * 2; u++) stA(tt, u);
    for (int u = 0; u < 4; u++) stB(tt, u);
  }
  if (nk > 1) {
    if constexpr (BMH == 2) asm volatile("s_waitcnt vmcnt(8)" ::: "memory");
    else asm volatile("s_waitcnt vmcnt(6)" ::: "memory");
  } else {
    asm volatile("s_waitcnt vmcnt(0)" ::: "memory");
  }
  __builtin_amdgcn_s_barrier();
  __builtin_amdgcn_sched_barrier(0);

  for (int t = 0; t < nk; t++) {
    const char* Ac = (const char*)As[t & 1];
    const char* Bc = (const char*)Bs[t & 1];
    bool pf = (t + 2 < nk);

    // P1: ds_read af0 + ALL B-frags; MFMA (mh0, nh0)
    bf16x8_t af0[4][2], bfr[4][2];
#pragma unroll
    for (int i = 0; i < 4; i++) {
      int row = wrb + i * 16 + l15;
#pragma unroll
      for (int kk = 0; kk < 2; kk++)
        af0[i][kk] = *(const bf16x8_t*)(Ac + ((row * 128 + kk * 64 + lg * 16) ^ xr));
    }
#pragma unroll
    for (int jn = 0; jn < 4; jn++) {
      int rowb = wcb + jn * 16 + l15;
#pragma unroll
      for (int kk = 0; kk < 2; kk++)
        bfr[jn][kk] = *(const bf16x8_t*)(Bc + ((rowb * 128 + kk * 64 + lg * 16) ^ xr));
    }
    __builtin_amdgcn_s_barrier();
    __builtin_amdgcn_s_setprio(1);
    if constexpr (BMH == 2) {
#pragma unroll
      for (int i = 0; i < 4; i++)
#pragma unroll
        for (int j = 0; j < 2; j++)
#pragma unroll
          for (int kk = 0; kk < 2; kk++)
            acc[i][j] = __builtin_amdgcn_mfma_f32_16x16x32_bf16(af0[i][kk], bfr[j][kk],
                                                                acc[i][j], 0, 0, 0);
    } else {
#pragma unroll
      for (int i = 0; i < 4; i++)
#pragma unroll
        for (int kk = 0; kk < 2; kk++)
          acc[i][0] = __builtin_amdgcn_mfma_f32_16x16x32_bf16(af0[i][kk], bfr[0][kk],
                                                              acc[i][0], 0, 0, 0);
    }
    __builtin_amdgcn_s_setprio(0);

    // P2: issue A granules freed at P1; MFMA (mh0, nh1)
    if (pf) {
      stA(t + 2, 0);
      if constexpr (BMH == 2) stA(t + 2, 2);
      else stA(t + 2, 1);
    }
    __builtin_amdgcn_s_barrier();
    __builtin_amdgcn_s_setprio(1);
    if constexpr (BMH == 2) {
#pragma unroll
      for (int i = 0; i < 4; i++)
#pragma unroll
        for (int j = 0; j < 2; j++)
#pragma unroll
          for (int kk = 0; kk < 2; kk++)
            acc[i][2 + j] = __builtin_amdgcn_mfma_f32_16x16x32_bf16(
                af0[i][kk], bfr[2 + j][kk], acc[i][2 + j], 0, 0, 0);
    } else {
#pragma unroll
      for (int i = 0; i < 4; i++)
#pragma unroll
        for (int kk = 0; kk < 2; kk++)
          acc[i][1] = __builtin_amdgcn_mfma_f32_16x16x32_bf16(af0[i][kk], bfr[1][kk],
                                                              acc[i][1], 0, 0, 0);
    }
    __builtin_amdgcn_s_setprio(0);

    // P3: (BMH=2) ds_read af1; issue B0,B1; MFMA
    bf16x8_t af1[4][2];
    if constexpr (BMH == 2) {
#pragma unroll
      for (int i = 0; i < 4; i++) {
        int row = wrb + 64 + i * 16 + l15;
#pragma unroll
        for (int kk = 0; kk < 2; kk++)
          af1[i][kk] = *(const bf16x8_t*)(Ac + ((row * 128 + kk * 64 + lg * 16) ^ xr));
      }
    }
    if (pf) { stB(t + 2, 0); stB(t + 2, 1); }
    __builtin_amdgcn_s_barrier();
    __builtin_amdgcn_s_setprio(1);
    if constexpr (BMH == 2) {
#pragma unroll
      for (int i = 0; i < 4; i++)
#pragma unroll
        for (int j = 0; j < 2; j++)
#pragma unroll
          for (int kk = 0; kk < 2; kk++)
            acc[4 + i][j] = __builtin_amdgcn_mfma_f32_16x16x32_bf16(
                af1[i][kk], bfr[j][kk], acc[4 + i][j], 0, 0, 0);
    } else {
#pragma unroll
      for (int i = 0; i < 4; i++)
#pragma unroll
        for (int kk = 0; kk < 2; kk++)
          acc[i][2] = __builtin_amdgcn_mfma_f32_16x16x32_bf16(af0[i][kk], bfr[2][kk],
                                                              acc[i][2], 0, 0, 0);
    }
    __builtin_amdgcn_s_setprio(0);

    // P4: issue B2,B3 (+A1,A3 for BMH=2); MFMA
    if (pf) {
      stB(t + 2, 2); stB(t + 2, 3);
      if constexpr (BMH == 2) { stA(t + 2, 1); stA(t + 2, 3); }
    }
    __builtin_amdgcn_s_barrier();
    __builtin_amdgcn_s_setprio(1);
    if constexpr (BMH == 2) {
#pragma unroll
      for (int i = 0; i < 4; i++)
#pragma unroll
        for (int j = 0; j < 2; j++)
#pragma unroll
          for (int kk = 0; kk < 2; kk++)
            acc[4 + i][2 + j] = __builtin_amdgcn_mfma_f32_16x16x32_bf16(
                af1[i][kk], bfr[2 + j][kk], acc[4 + i][2 + j], 0, 0, 0);
    } else {
#pragma unroll
      for (int i = 0; i < 4; i++)
#pragma unroll
        for (int kk = 0; kk < 2; kk++)
          acc[i][3] = __builtin_amdgcn_mfma_f32_16x16x32_bf16(af0[i][kk], bfr[3][kk],
                                                              acc[i][3], 0, 0, 0);
    }
    __builtin_amdgcn_s_setprio(0);

    if (t + 1 < nk) {
      if (pf) {
        if constexpr (BMH == 2) asm volatile("s_waitcnt vmcnt(8)" ::: "memory");
        else asm volatile("s_waitcnt vmcnt(6)" ::: "memory");
      } else {
        asm volatile("s_waitcnt vmcnt(0)" ::: "memory");
      }
    }
    __builtin_amdgcn_s_barrier();
    __builtin_amdgcn_sched_barrier(0);
  }

  if (EPI == 2) {
    if (col0 < VOFF) {
      int sbase = row0 & (S_LEN - 1);
      bf16_t* cosL = &As[0][0];
      bf16_t* sinL = &Bs[0][0];
#pragma unroll
      for (int k = 0; k < 8; k++) {
        gload_lds16((const bf16_t*)(cosT + (size_t)sbase * 64 + k * 2048 + tid * 4),
                    cosL + k * 4096 + tid * 8);
        gload_lds16((const bf16_t*)(sinT + (size_t)sbase * 64 + k * 2048 + tid * 4),
                    sinL + k * 4096 + tid * 8);
      }
      asm volatile("s_waitcnt vmcnt(0)" ::: "memory");
      __builtin_amdgcn_s_barrier();
      const float* cosF = (const float*)cosL;
      const float* sinF = (const float*)sinL;
      const float QS = 0.08838834764831845f * 1.4426950408889634f;
#pragma unroll
      for (int i = 0; i < BMH * 4; i++) {
#pragma unroll
        for (int j = 0; j < 4; j++) {
          int c = col0 + wcb + j * 16 + l15;
          int rlb = wrb + i * 16 + lg * 4;
          float scale = (c < KOFF) ? QS : 1.0f;
          int p0 = (c & 127) >> 1;
          int codd = c & 1;
#pragma unroll
          for (int qd = 0; qd < 4; qd++) {
            int rl = rlb + qd;
            float self = acc[i][j][qd];
            float other = __shfl_xor(self, 1);
            float cv = cosF[rl * 64 + p0], sv = sinF[rl * 64 + p0];
            float outv = codd ? (self * cv + other * sv) : (self * cv - other * sv);
            ((bf16_t*)Cout)[(size_t)(row0 + rl) * N + c] = (bf16_t)(outv * scale);
          }
        }
      }
    } else {
#pragma unroll
      for (int i = 0; i < BMH * 4; i++) {
#pragma unroll
        for (int j = 0; j < 4; j++) {
          int r = row0 + wrb + i * 16 + lg * 4;
          int c = col0 + wcb + j * 16 + l15;
#pragma unroll
          for (int qd = 0; qd < 4; qd++)
            ((bf16_t*)Cout)[(size_t)(r + qd) * N + c] = (bf16_t)acc[i][j][qd];
        }
      }
    }
  } else {
#pragma unroll
    for (int i = 0; i < BMH * 4; i++) {
#pragma unroll
      for (int j = 0; j < 4; j++) {
        int r = row0 + wrb + i * 16 + lg * 4;
        int c = col0 + wcb + j * 16 + l15;
#pragma unroll
        for (int qd = 0; qd < 4; qd++)
          ((float*)Cout)[(size_t)(r + qd) * N + c] = acc[i][j][qd];
      }
    }
  }
}

// ---------------- V -> Vt relayout: vt[b][kvh][d][s] -----------------------
__global__ __launch_bounds__(256) void k_vt(const bf16_t* __restrict__ qkv,
                                            bf16_t* __restrict__ vt) {
  __shared__ bf16_t t[32][33];
  int s0 = blockIdx.x * 32;
  int dt = (blockIdx.y & 3) * 32;
  int h = blockIdx.y >> 2;
  int b = blockIdx.z;
  int tx = threadIdx.x & 31, ty = threadIdx.x >> 5;
#pragma unroll
  for (int rr = ty; rr < 32; rr += 8)
    t[rr][tx] = qkv[(size_t)(b * S_LEN + s0 + rr) * QKVN + VOFF + h * HD + dt + tx];
  __syncthreads();
#pragma unroll
  for (int rr = ty; rr < 32; rr += 8)
    vt[((size_t)((b * NKVH + h) * HD + dt + rr)) * S_LEN + s0 + tx] = t[tx][rr];
}

// ---------------- flash attention: 4 waves, QBLK=64 (R12/R13 verified) -----
__global__ __launch_bounds__(256, 2) void k_attn(const bf16_t* __restrict__ qkv,
                                                 const bf16_t* __restrict__ vt,
                                                 bf16_t* __restrict__ ctx) {
  __shared__ bf16_t Ks[2 * 64 * 128];
  __shared__ bf16_t Vs[2 * 128 * 64];
  __shared__ bf16_t plds[4][16 * 72];

  int tid = threadIdx.x;
  int lane = tid & 63, wid = tid >> 6;
  int idx = blockIdx.x;
  int bh = idx & 31;
  int qg = 31 - (idx >> 5);
  int b = bh >> 4, h = bh & 15;
  int kvh = h >> 2;
  int q0 = qg * 64 + wid * 16;
  int l15 = lane & 15, lg = lane >> 4;

  const bf16_t* Kbase = qkv + (size_t)(b * S_LEN) * QKVN + KOFF + kvh * HD;
  const bf16_t* Vbase = vt + (size_t)(b * NKVH + kvh) * HD * S_LEN;

  const bf16_t* Qp = qkv + (size_t)(b * S_LEN + q0 + l15) * QKVN + h * HD + lg * 8;
  bf16x8_t aq[4];
#pragma unroll
  for (int kk = 0; kk < 4; kk++) aq[kk] = *(const bf16x8_t*)(Qp + kk * 32);

  int Ls[4], Lk[4], Lv[4];
#pragma unroll
  for (int u = 0; u < 4; u++) {
    int L = u * 4096 + tid * 16;
    Ls[u] = L >> 1;
    Lk[u] = L ^ (((L >> 8) & 7) << 4);
    Lv[u] = L ^ (((L >> 7) & 7) << 4);
  }

  f32x4_t o[8];
#pragma unroll
  for (int j = 0; j < 8; j++) o[j] = zero4();
  float ms = -INFINITY, lsum = 0.f;

  bf16_t* pbuf = &plds[wid][0];
  int xr = (l15 & 7) << 4;
  int ntiles = qg + 1;
  int qcol = q0 + l15;

#pragma unroll
  for (int u = 0; u < 4; u++) {
    gload_lds16(Kbase + (size_t)(Lk[u] >> 8) * QKVN + ((Lk[u] & 255) >> 1), Ks + Ls[u]);
    gload_lds16(Vbase + (size_t)(Lv[u] >> 7) * S_LEN + ((Lv[u] & 127) >> 1), Vs + Ls[u]);
  }
  __syncthreads();

  for (int t = 0; t < ntiles; t++) {
    int kv0 = t * 64;
    if (t + 1 < ntiles) {
      const bf16_t* Kn = Kbase + (size_t)(kv0 + 64) * QKVN;
      const bf16_t* Vn = Vbase + kv0 + 64;
      int bo = ((t + 1) & 1) * 8192;
#pragma unroll
      for (int u = 0; u < 4; u++) {
        gload_lds16(Kn + (size_t)(Lk[u] >> 8) * QKVN + ((Lk[u] & 255) >> 1), Ks + bo + Ls[u]);
        gload_lds16(Vn + (size_t)(Lv[u] >> 7) * S_LEN + ((Lv[u] & 127) >> 1), Vs + bo + Ls[u]);
      }
    }
    const char* Kb = (const char*)Ks + (t & 1) * 16384;
    const char* Vb = (const char*)Vs + (t & 1) * 16384;

    f32x4_t sacc[4];
#pragma unroll
    for (int cg = 0; cg < 4; cg++) sacc[cg] = zero4();
#pragma unroll
    for (int cg = 0; cg < 4; cg++) {
#pragma unroll
      for (int kk = 0; kk < 4; kk++) {
        int boff = ((cg * 16 + l15) * 256 + kk * 64 + lg * 16) ^ xr;
        bf16x8_t bk = *(const bf16x8_t*)(Kb + boff);
        sacc[cg] = __builtin_amdgcn_mfma_f32_16x16x32_bf16(bk, aq[kk], sacc[cg], 0, 0, 0);
      }
    }
    if (kv0 + 63 > q0) {
#pragma unroll
      for (int cg = 0; cg < 4; cg++) {
#pragma unroll
        for (int i = 0; i < 4; i++) {
          int kvg = kv0 + cg * 16 + lg * 4 + i;
          if (kvg > qcol) sacc[cg][i] = -1e30f;
        }
      }
    }
    float pmax = sacc[0][0];
#pragma unroll
    for (int cg = 0; cg < 4; cg++)
#pragma unroll
      for (int i = 0; i < 4; i++) pmax = fmaxf(pmax, sacc[cg][i]);
    pmax = fmaxf(pmax, __shfl_xor(pmax, 16));
    pmax = fmaxf(pmax, __shfl_xor(pmax, 32));
    if (__any(pmax - ms > 8.0f)) {
      float nm = fmaxf(ms, pmax);
      float sc = fexp2(ms - nm);
      ms = nm;
      lsum *= sc;
      float sci[4];
#pragma unroll
      for (int i = 0; i < 4; i++) sci[i] = __shfl(sc, lg * 4 + i);
#pragma unroll
      for (int j = 0; j < 8; j++)
#pragma unroll
        for (int i = 0; i < 4; i++) o[j][i] *= sci[i];
    }
    float ls = 0.f;
#pragma unroll
    for (int cg = 0; cg < 4; cg++)
#pragma unroll
      for (int i = 0; i < 4; i++) {
        sacc[cg][i] = fexp2(sacc[cg][i] - ms);
        ls += sacc[cg][i];
      }
    ls += __shfl_xor(ls, 16);
    ls += __shfl_xor(ls, 32);
    lsum += ls;
#pragma unroll
    for (int cg = 0; cg < 4; cg++)
#pragma unroll
      for (int i = 0; i < 4; i++)
        pbuf[l15 * 72 + cg * 16 + lg * 4 + i] = (bf16_t)sacc[cg][i];
    __builtin_amdgcn_wave_barrier();
    bf16x8_t pa0 = *(const bf16x8_t*)(pbuf + l15 * 72 + lg * 8);
    bf16x8_t pa1 = *(const bf16x8_t*)(pbuf + l15 * 72 + 32 + lg * 8);
    __builtin_amdgcn_wave_barrier();
#pragma unroll
    for (int j = 0; j < 8; j++) {
      int d = j * 16 + l15;
      int bo0 = (d * 128 + lg * 16) ^ xr;
      int bo1 = (d * 128 + 64 + lg * 16) ^ xr;
      o[j] = __builtin_amdgcn_mfma_f32_16x16x32_bf16(
          pa0, *(const bf16x8_t*)(Vb + bo0), o[j], 0, 0, 0);
      o[j] = __builtin_amdgcn_mfma_f32_16x16x32_bf16(
          pa1, *(const bf16x8_t*)(Vb + bo1), o[j], 0, 0, 0);
    }
    __syncthreads();
  }

  bf16_t* Cp = ctx + (size_t)(b * S_LEN + q0) * KOFF + h * HD;
#pragma unroll
  for (int i = 0; i < 4; i++) {
    float inv = 1.f / __shfl(lsum, lg * 4 + i);
    int row = lg * 4 + i;
#pragma unroll
    for (int j = 0; j < 8; j++)
      Cp[(size_t)row * KOFF + j * 16 + l15] = (bf16_t)(o[j][i] * inv);
  }
}

extern "C" void kernel_launch(void* const* d_in, const int* in_sizes, int n_in,
                              void* d_out, int out_size, void* d_ws, size_t ws_size,
                              hipStream_t stream) {
  const float* x = (const float*)d_in[0];
  const float* wq = (const float*)d_in[1];
  const float* wk = (const float*)d_in[2];
  const float* wv = (const float*)d_in[3];
  const float* wo = (const float*)d_in[4];
  const float* cosT = (const float*)d_in[5];
  const float* sinT = (const float*)d_in[6];

  bf16_t* xb = (bf16_t*)d_ws;                          // 4096x2048 (later reused as ctx)
  bf16_t* wqkvT = xb + (size_t)MROWS * HIDW;           // 3072x2048
  bf16_t* woT = wqkvT + (size_t)QKVN * HIDW;           // 2048x2048
  bf16_t* qkv = woT + (size_t)HIDW * HIDW;             // 4096x3072
  bf16_t* vtb = qkv + (size_t)MROWS * QKVN;            // 2*4*128*2048

  // 1) convert x
  k_cvt8<<<MROWS * HIDW / 8 / 256, 256, 0, stream>>>(x, xb, MROWS * HIDW / 8);
  // 2) weight transposes: merged wq|wk|wv -> wqkvT, plus wo -> woT
  k_tr_qkvw<<<dim3(QKVN / 32, HIDW / 32), 256, 0, stream>>>(wq, wk, wv, wqkvT);
  k_tr_cvt<<<dim3(HIDW / 32, KOFF / 32), 256, 0, stream>>>(wo, woT, KOFF, HIDW);
  // 3) QKV projection (R13 best-measured) + fused rope epilogue
  k_gemm256<2, 2><<<(MROWS / 256) * (QKVN / 256), 512, 0, stream>>>(
      xb, wqkvT, qkv, MROWS, QKVN, HIDW, QKVN / 256, cosT, sinT);
  // 4) V transpose
  k_vt<<<dim3(S_LEN / 32, 4 * NKVH, NB), 256, 0, stream>>>(qkv, vtb);
  // 5) attention (R12/R13-verified; ctx -> xb region)
  k_attn<<<32 * 32, 256, 0, stream>>>(qkv, vtb, xb);
  // 6) output projection -> f32 d_out (R13 counted schedule, 256 blocks)
  k_gemm256<0, 1><<<(MROWS / 128) * (HIDW / 256), 512, 0, stream>>>(
      xb, woT, d_out, MROWS, HIDW, KOFF, HIDW / 256, nullptr, nullptr);
}